// Round 9
// baseline (1169.660 us; speedup 1.0000x reference)
//
#include <hip/hip_runtime.h>
#include <hip/hip_bf16.h>
#include <stdint.h>

// Problem dims
#define BATCH 256
#define SEQ   512
#define INDIM 64
#define H     128
#define RB    4                 // batch rows per recurrence block
#define NTILE 64                // batch tiles
#define CH    16                // pipeline chunk (steps)
#define NCH   (SEQ / CH)        // 32 chunks
#define RD    2                 // ring depth (slots)

// workspace layout (bytes)
#define WS_XB     0u            // bf16[256*512*64]          16,777,216
#define WS_H0RING 16777216u     // bf16[64][2][16*4][128]     2,097,152
#define WS_G0RING 18874368u     // f32 [64][2][16][512][4]   16,777,216
#define WS_G1RING 35651584u     // f32 [64][2][16][512][4]   16,777,216
#define WS_WB     52428800u     // bf16 weights 229376 elems    458,752
#define WS_BSUM   52887552u     // f32[1024]                      4,096
#define WS_FLAGS  52891648u     // int[256]                       1,024
// wb element offsets
#define WB_IH0 0
#define WB_HH0 32768
#define WB_IH1 98304
#define WB_HH1 163840
#define WB_TOT 229376

using short8  = __attribute__((ext_vector_type(8))) short;
using float4v = __attribute__((ext_vector_type(4))) float;

#define LOG2E 1.4426950408889634f

__device__ __forceinline__ unsigned short f2bf(float f) {
    union { float f; uint32_t u; } v; v.f = f;
    uint32_t u = v.u;
    return (unsigned short)((u + 0x7FFFu + ((u >> 16) & 1u)) >> 16); // RNE
}
__device__ __forceinline__ float fast_exp2(float x) {
#if __has_builtin(__builtin_amdgcn_exp2f)
    return __builtin_amdgcn_exp2f(x);
#else
    return __expf(x * 0.6931471805599453f);
#endif
}
__device__ __forceinline__ float fast_rcp(float x) {
#if __has_builtin(__builtin_amdgcn_rcpf)
    return __builtin_amdgcn_rcpf(x);
#else
    return 1.f / x;
#endif
}
__device__ __forceinline__ float sigmoid_fast(float x) {
    return fast_rcp(1.f + fast_exp2(-LOG2E * x));
}
__device__ __forceinline__ float tanh_fast(float x) {
    return fmaf(-2.f, fast_rcp(1.f + fast_exp2((2.f * LOG2E) * x)), 1.f);
}
// LDS-only per-step barrier (global loads/stores stay in flight)
__device__ __forceinline__ void light_barrier() {
    asm volatile("s_waitcnt lgkmcnt(0)\n\ts_barrier" ::: "memory");
}
__device__ __forceinline__ void spin_ge(const int* f, int target) {
    while (__hip_atomic_load(f, __ATOMIC_RELAXED, __HIP_MEMORY_SCOPE_AGENT) < target)
        __builtin_amdgcn_s_sleep(2);
    (void)__hip_atomic_load(f, __ATOMIC_ACQUIRE, __HIP_MEMORY_SCOPE_AGENT);
}
__device__ __forceinline__ void bump(int* f) {
    __hip_atomic_fetch_add(f, 1, __ATOMIC_RELEASE, __HIP_MEMORY_SCOPE_AGENT);
}

// ---------------- prep 1: x fp32 -> bf16 ----------------
__global__ void conv_x_kernel(const float* __restrict__ x, unsigned short* __restrict__ xb) {
    int i = blockIdx.x * blockDim.x + threadIdx.x;   // grid covers exactly 2,097,152 float4s
    float4 f = ((const float4*)x)[i];
    ushort4 o;
    o.x = f2bf(f.x); o.y = f2bf(f.y); o.z = f2bf(f.z); o.w = f2bf(f.w);
    ((ushort4*)xb)[i] = o;
}

// ---------------- prep 2: weights->bf16, bias sums, flag zero ----------------
__global__ void prep_w_kernel(const float* __restrict__ Wih0, const float* __restrict__ Whh0,
                              const float* __restrict__ Wih1, const float* __restrict__ Whh1,
                              const float* __restrict__ bih0, const float* __restrict__ bhh0,
                              const float* __restrict__ bih1, const float* __restrict__ bhh1,
                              unsigned short* __restrict__ wb, float* __restrict__ bsum,
                              int* __restrict__ flags) {
    int gid = blockIdx.x * blockDim.x + threadIdx.x;   // grid = 896*256 = 229376 = WB_TOT
    float v;
    if      (gid < WB_HH0) v = Wih0[gid];
    else if (gid < WB_IH1) v = Whh0[gid - WB_HH0];
    else if (gid < WB_HH1) v = Wih1[gid - WB_IH1];
    else                   v = Whh1[gid - WB_HH1];
    wb[gid] = f2bf(v);
    if (gid < 512)       bsum[gid] = bih0[gid] + bhh0[gid];
    else if (gid < 1024) bsum[gid] = bih1[gid - 512] + bhh1[gid - 512];
    if (gid < 256) flags[gid] = 0;
}

// ---------------- helper GEMM: gslot = bsum + A @ Wih^T (one chunk, one tile) ----------------
// 8 waves; wave w covers n-tiles w*4..w*4+3 (all 512 gate cols), m = 64 tokens (4 m-tiles).
// Output written directly in the recurrence's acc-init layout [step i][tid 512][4 gates] f32,
// using the verified C-layout: col=lane&15, row=(lane>>4)*4+reg. token m = step*4 + row.
template<bool L0>
__device__ __forceinline__ void gates_gemm(
    const unsigned short* __restrict__ abase,  // L0: xb (global layout); else h0 slot [m][128]
    const unsigned short* __restrict__ wih,    // bf16 [512][K]
    const float* __restrict__ bsum,            // [512]
    float* __restrict__ gslot,                 // [16][512][4] f32
    int b0, int t0, int w, int lane)
{
    constexpr int K  = L0 ? INDIM : H;
    constexpr int KT = K / 32;
    const int quad = lane >> 4, l16 = lane & 15;

    short8 af[4][KT];                          // A-frags for 4 m-tiles (static indexing only)
#pragma unroll
    for (int mt = 0; mt < 4; mt++) {
        const int m = mt * 16 + l16;           // token index; step = m>>2, row = m&3
        const unsigned short* ap = L0
            ? abase + ((size_t)(b0 + (m & 3)) * SEQ + (t0 + (m >> 2))) * INDIM + quad * 8
            : abase + (size_t)m * H + quad * 8;
#pragma unroll
        for (int kt = 0; kt < KT; kt++) af[mt][kt] = *(const short8*)(ap + kt * 32);
    }
#pragma unroll
    for (int j = 0; j < 4; j++) {
        const int n = (w * 4 + j) * 16 + l16;  // gate column
        short8 bf[KT];
#pragma unroll
        for (int kt = 0; kt < KT; kt++)
            bf[kt] = *(const short8*)(wih + (size_t)n * K + kt * 32 + quad * 8);
        const float bs = bsum[n];
        const int cellc = n & 127, tT = n >> 7;
#pragma unroll
        for (int mt = 0; mt < 4; mt++) {
            float4v acc = (float4v){bs, bs, bs, bs};
#pragma unroll
            for (int kt = 0; kt < KT; kt++)
                acc = __builtin_amdgcn_mfma_f32_16x16x32_bf16(af[mt][kt], bf[kt], acc, 0, 0, 0);
#pragma unroll
            for (int reg = 0; reg < 4; reg++) {
                const int m_out = mt * 16 + quad * 4 + reg;   // C row
                const int io = m_out >> 2, ro = m_out & 3;    // step, batch-row
                const int tidr = (cellc >> 4) * 64 + ro * 16 + (cellc & 15);
                gslot[((size_t)io * 512 + tidr) * 4 + tT] = acc[reg];
            }
        }
    }
}

// ---------------- recurrence (producer=layer0 / consumer=layer1+head) ----------------
// Slim per-step: prefetched dwordx4 acc-init (bias + x-partial, from ring) -> ds_read h ->
// 16 MFMAs -> 1 cell update/lane -> ds_write (+ producer h0-ring store) -> light barrier.
// R8 BUG FIX: the gate-init prefetch must write the SAME buffer that was just consumed
// (gi holds step i; after reading it, overwrite with step i+2). R8 prefetched into the
// OTHER buffer, clobbering step i+1's init -> every in-chunk step after 0 used a shifted
// x-projection (absmax 8.3e-3).
template<bool IS_PROD>
__device__ __forceinline__ void lstm_rec(
    const unsigned short* __restrict__ wb_hh,  // bf16 [512][128]
    const float* __restrict__ gring,           // its gate ring (g0 or g1)
    unsigned short* __restrict__ h0ring,       // producer writes h chunks here
    const float* __restrict__ W1, const float* __restrict__ b1,
    const float* __restrict__ W2, const float* __restrict__ b2,
    float* __restrict__ out,
    int* g0rdy, int* g1rdy, int* prodprog, int* consprog, int bt)
{
    const int tid  = threadIdx.x;
    const int lane = tid & 63, w = tid >> 6, quad = lane >> 4, l16 = lane & 15;
    const int b0   = bt * RB;
    const int cell = w * 16 + l16;
    const int arow = l16 & 12;

    __shared__ short hbuf[2][16][132];         // pad 132: 66 dwords == 2 mod 32 (free 2-way)
    __shared__ float hl[RB][128];
    __shared__ float mid[RB][65];
    for (int i = tid; i < 2 * 16 * 132; i += 512) ((short*)hbuf)[i] = 0;

    short8 whh_f[4][4];                        // the ONLY weights this block holds
#pragma unroll
    for (int tT = 0; tT < 4; tT++)
#pragma unroll
        for (int kt = 0; kt < 4; kt++)
            whh_f[tT][kt] = *(const short8*)(wb_hh + (size_t)(tT * 128 + cell) * H + kt * 32 + quad * 8);

    const float4* gbase = (const float4*)gring + (size_t)bt * (RD * CH * 512);
    unsigned short* hbase = IS_PROD ? h0ring + (size_t)bt * (RD * CH * RB * H) : nullptr;

    float  c0 = 0.f;
    float4 giA, giB;                           // static double-buffered acc-init
    __syncthreads();

    // gi: holds step i's init on entry; consumed, then (doPre) overwritten with step i+2's.
    auto rstep = [&](int i, int CUR, float4& gi,
                     const float4* gs, unsigned short* hs, bool doPre, bool lastStep)
        __attribute__((always_inline)) {
        short8 ha[4];
#pragma unroll
        for (int kt = 0; kt < 4; kt++)
            ha[kt] = *(const short8*)&hbuf[CUR][arow][kt * 32 + quad * 8];
        float4v a0 = (float4v){gi.x, 0.f, 0.f, 0.f};
        float4v a1 = (float4v){gi.y, 0.f, 0.f, 0.f};
        float4v a2 = (float4v){gi.z, 0.f, 0.f, 0.f};
        float4v a3 = (float4v){gi.w, 0.f, 0.f, 0.f};
#pragma unroll
        for (int kt = 0; kt < 4; kt++) {
            a0 = __builtin_amdgcn_mfma_f32_16x16x32_bf16(ha[kt], whh_f[0][kt], a0, 0, 0, 0);
            a1 = __builtin_amdgcn_mfma_f32_16x16x32_bf16(ha[kt], whh_f[1][kt], a1, 0, 0, 0);
            a2 = __builtin_amdgcn_mfma_f32_16x16x32_bf16(ha[kt], whh_f[2][kt], a2, 0, 0, 0);
            a3 = __builtin_amdgcn_mfma_f32_16x16x32_bf16(ha[kt], whh_f[3][kt], a3, 0, 0, 0);
        }
        if (doPre) gi = gs[(size_t)(i + 2) * 512 + tid];   // prefetch step i+2 into freed buffer
        float si = sigmoid_fast(a0[0]);
        float sf = sigmoid_fast(a1[0]);
        float tg = tanh_fast(a2[0]);
        float so = sigmoid_fast(a3[0]);
        float cn = fmaf(sf, c0, si * tg);
        c0 = cn;
        float h = so * tanh_fast(cn);
        const unsigned short hb = f2bf(h);
        hbuf[CUR ^ 1][quad * 4][cell] = (short)hb;
        if (IS_PROD) {
            hs[(size_t)(i * 4 + quad) * H + cell] = hb;    // fire-and-forget
        } else if (lastStep) {
            hl[quad][cell] = h;
        }
        light_barrier();
    };

    for (int ch = 0; ch < NCH; ch++) {
        if (tid == 0) {
            spin_ge(IS_PROD ? &g0rdy[bt] : &g1rdy[bt], ch + 1);
            if (IS_PROD && ch >= 2) spin_ge(&g1rdy[bt], ch - 1);   // h0 slot free
        }
        __syncthreads();
        const float4*   gs = gbase + (size_t)(ch & 1) * (CH * 512);
        unsigned short* hs = IS_PROD ? hbase + (size_t)(ch & 1) * (CH * RB * H) : nullptr;
        giA = gs[tid];
        giB = gs[512 + tid];
        const bool lastCh = (ch == NCH - 1);
#pragma unroll 1
        for (int i = 0; i < CH; i += 2) {
            rstep(i,     0, giA, gs, hs, i + 2 < CH, false);
            rstep(i + 1, 1, giB, gs, hs, i + 3 < CH, lastCh && (i + 1 == CH - 1));
        }
        __syncthreads();                        // drains producer ring stores (vmcnt)
        if (tid == 0) bump(IS_PROD ? &prodprog[bt] : &consprog[bt]);
    }

    if (!IS_PROD) {
        // MLP head for this block's RB rows
        if (tid < RB * 64) {
            const int row = tid >> 6, j = tid & 63;
            float s = b1[j];
            const float* wr = W1 + (size_t)j * 128;
#pragma unroll 8
            for (int k = 0; k < 128; k++) s = fmaf(hl[row][k], wr[k], s);
            mid[row][j] = fmaxf(s, 0.f);
        }
        __syncthreads();
        if (tid < RB * 3) {
            const int row = tid / 3, k = tid - row * 3;
            float o = b2[k];
            const float* wr = W2 + (size_t)k * 64;
#pragma unroll 8
            for (int j = 0; j < 64; j++) o = fmaf(mid[row][j], wr[j], o);
            out[(size_t)(b0 + row) * 3 + k] = o;
        }
    }
}

// ---------------- helper block: gates0(ch) then gates1(ch-1) per iteration ----------------
// Ordering keeps the producer's next g0 chunk always ready before it needs it.
__device__ __forceinline__ void helper_body(
    const unsigned short* __restrict__ xb, const unsigned short* __restrict__ h0ring,
    const unsigned short* __restrict__ wb, const float* __restrict__ bsum,
    float* __restrict__ g0ring, float* __restrict__ g1ring,
    int* g0rdy, int* g1rdy, int* prodprog, int* consprog, int bt)
{
    const int tid = threadIdx.x, w = tid >> 6, lane = tid & 63;
    const int b0 = bt * RB;
    float* g0base = g0ring + (size_t)bt * (RD * CH * 512 * 4);
    float* g1base = g1ring + (size_t)bt * (RD * CH * 512 * 4);
    const unsigned short* h0base = h0ring + (size_t)bt * (RD * CH * RB * H);

    for (int ch = 0; ch < NCH; ch++) {
        // ---- gates0(ch): slot free once producer finished ch-2
        if (ch >= 2) { if (tid == 0) spin_ge(&prodprog[bt], ch - 1); __syncthreads(); }
        gates_gemm<true>(xb, wb + WB_IH0, bsum,
                         g0base + (size_t)(ch & 1) * (CH * 512 * 4), b0, ch * CH, w, lane);
        __syncthreads();                        // drain stores
        if (tid == 0) bump(&g0rdy[bt]);
        // ---- gates1(ch-1): needs h0(ch-1) (prodprog>=ch) and slot free (consprog>=ch-3)
        if (ch >= 1) {
            const int c1 = ch - 1;
            if (tid == 0) { spin_ge(&prodprog[bt], c1 + 1); if (c1 >= 2) spin_ge(&consprog[bt], c1 - 1); }
            __syncthreads();
            gates_gemm<false>(h0base + (size_t)(c1 & 1) * (CH * RB * H), wb + WB_IH1, bsum + 512,
                              g1base + (size_t)(c1 & 1) * (CH * 512 * 4), b0, 0, w, lane);
            __syncthreads();
            if (tid == 0) bump(&g1rdy[bt]);
        }
    }
    // ---- final gates1(NCH-1)
    {
        const int c1 = NCH - 1;
        if (tid == 0) { spin_ge(&prodprog[bt], c1 + 1); spin_ge(&consprog[bt], c1 - 1); }
        __syncthreads();
        gates_gemm<false>(h0base + (size_t)(c1 & 1) * (CH * RB * H), wb + WB_IH1, bsum + 512,
                          g1base + (size_t)(c1 & 1) * (CH * 512 * 4), b0, 0, w, lane);
        __syncthreads();
        if (tid == 0) bump(&g1rdy[bt]);
    }
}

__global__ __launch_bounds__(512, 2)
void lstm_fused_kernel(const unsigned short* __restrict__ xb,
                       const unsigned short* __restrict__ wb,
                       const float* __restrict__ bsum,
                       float* __restrict__ g0ring, float* __restrict__ g1ring,
                       unsigned short* __restrict__ h0ring,
                       const float* __restrict__ W1, const float* __restrict__ b1,
                       const float* __restrict__ W2, const float* __restrict__ b2,
                       float* __restrict__ out, int* __restrict__ flags)
{
    int* g0rdy    = flags;
    int* g1rdy    = flags + 64;
    int* prodprog = flags + 128;
    int* consprog = flags + 192;
    if (blockIdx.x < 64) {
        lstm_rec<true >(wb + WB_HH0, g0ring, h0ring, W1, b1, W2, b2, out,
                        g0rdy, g1rdy, prodprog, consprog, blockIdx.x);
    } else if (blockIdx.x < 128) {
        lstm_rec<false>(wb + WB_HH1, g1ring, nullptr, W1, b1, W2, b2, out,
                        g0rdy, g1rdy, prodprog, consprog, blockIdx.x - 64);
    } else {
        helper_body(xb, h0ring, wb, bsum, g0ring, g1ring,
                    g0rdy, g1rdy, prodprog, consprog, blockIdx.x - 128);
    }
}

extern "C" void kernel_launch(void* const* d_in, const int* in_sizes, int n_in,
                              void* d_out, int out_size, void* d_ws, size_t ws_size,
                              hipStream_t stream) {
    const float* x     = (const float*)d_in[0];
    const float* W_ih0 = (const float*)d_in[1];
    const float* W_hh0 = (const float*)d_in[2];
    const float* b_ih0 = (const float*)d_in[3];
    const float* b_hh0 = (const float*)d_in[4];
    const float* W_ih1 = (const float*)d_in[5];
    const float* W_hh1 = (const float*)d_in[6];
    const float* b_ih1 = (const float*)d_in[7];
    const float* b_hh1 = (const float*)d_in[8];
    const float* W1    = (const float*)d_in[9];
    const float* b1    = (const float*)d_in[10];
    const float* W2    = (const float*)d_in[11];
    const float* b2    = (const float*)d_in[12];
    float* out = (float*)d_out;

    char* ws = (char*)d_ws;
    unsigned short* xb   = (unsigned short*)(ws + WS_XB);
    unsigned short* h0r  = (unsigned short*)(ws + WS_H0RING);
    float*          g0r  = (float*)(ws + WS_G0RING);
    float*          g1r  = (float*)(ws + WS_G1RING);
    unsigned short* wb   = (unsigned short*)(ws + WS_WB);
    float*          bsum = (float*)(ws + WS_BSUM);
    int*            flags= (int*)(ws + WS_FLAGS);

    conv_x_kernel<<<8192, 256, 0, stream>>>(x, xb);
    prep_w_kernel<<<896, 256, 0, stream>>>(W_ih0, W_hh0, W_ih1, W_hh1,
                                           b_ih0, b_hh0, b_ih1, b_hh1, wb, bsum, flags);
    lstm_fused_kernel<<<192, 512, 0, stream>>>(xb, wb, bsum, g0r, g1r, h0r,
                                               W1, b1, W2, b2, out, flags);
}

// Round 10
// 523.690 us; speedup vs baseline: 2.2335x; 2.2335x over previous
//
#include <hip/hip_runtime.h>
#include <hip/hip_bf16.h>
#include <stdint.h>

// Problem dims
#define BATCH 256
#define SEQ   512
#define INDIM 64
#define H     128
#define RB    4                 // batch rows per block
#define NTILE 64                // batch tiles
#define CH    16                // inter-block h0 handoff chunk (steps)
#define NCH   (SEQ / CH)        // 32 chunks

// workspace layout (bytes)
#define WS_XB     0u            // bf16[256*512*64]             16,777,216
#define WS_H0RING 16777216u     // bf16[64 tiles][4 slots][64 tok][128]  4,194,304
#define WS_WB     20971520u     // bf16 weights 229376 elems       458,752
#define WS_BSUM   21430272u     // f32[1024]                         4,096
#define WS_FLAGS  21434368u     // int[128]                            512
// wb element offsets
#define WB_IH0 0
#define WB_HH0 32768
#define WB_IH1 98304
#define WB_HH1 163840
#define WB_TOT 229376

using short8  = __attribute__((ext_vector_type(8))) short;
using float4v = __attribute__((ext_vector_type(4))) float;

#define LOG2E 1.4426950408889634f

__device__ __forceinline__ unsigned short f2bf(float f) {
    union { float f; uint32_t u; } v; v.f = f;
    uint32_t u = v.u;
    return (unsigned short)((u + 0x7FFFu + ((u >> 16) & 1u)) >> 16); // RNE
}
__device__ __forceinline__ float fast_exp2(float x) {
#if __has_builtin(__builtin_amdgcn_exp2f)
    return __builtin_amdgcn_exp2f(x);
#else
    return __expf(x * 0.6931471805599453f);
#endif
}
__device__ __forceinline__ float fast_rcp(float x) {
#if __has_builtin(__builtin_amdgcn_rcpf)
    return __builtin_amdgcn_rcpf(x);
#else
    return 1.f / x;
#endif
}
__device__ __forceinline__ float sigmoid_fast(float x) {
    return fast_rcp(1.f + fast_exp2(-LOG2E * x));
}
__device__ __forceinline__ float tanh_fast(float x) {
    return fmaf(-2.f, fast_rcp(1.f + fast_exp2((2.f * LOG2E) * x)), 1.f);
}
// LDS-only per-step barrier (global loads/stores stay in flight)
__device__ __forceinline__ void light_barrier() {
    asm volatile("s_waitcnt lgkmcnt(0)\n\ts_barrier" ::: "memory");
}
__device__ __forceinline__ void spin_ge(const int* f, int target) {
    while (__hip_atomic_load(f, __ATOMIC_RELAXED, __HIP_MEMORY_SCOPE_AGENT) < target)
        __builtin_amdgcn_s_sleep(2);
    (void)__hip_atomic_load(f, __ATOMIC_ACQUIRE, __HIP_MEMORY_SCOPE_AGENT);
}
__device__ __forceinline__ void bump(int* f) {
    __hip_atomic_fetch_add(f, 1, __ATOMIC_RELEASE, __HIP_MEMORY_SCOPE_AGENT);
}

// ---------------- prep 1: x fp32 -> bf16 ----------------
__global__ void conv_x_kernel(const float* __restrict__ x, unsigned short* __restrict__ xb) {
    int i = blockIdx.x * blockDim.x + threadIdx.x;   // grid covers exactly 2,097,152 float4s
    float4 f = ((const float4*)x)[i];
    ushort4 o;
    o.x = f2bf(f.x); o.y = f2bf(f.y); o.z = f2bf(f.z); o.w = f2bf(f.w);
    ((ushort4*)xb)[i] = o;
}

// ---------------- prep 2: weights->bf16, bias sums, flag zero ----------------
__global__ void prep_w_kernel(const float* __restrict__ Wih0, const float* __restrict__ Whh0,
                              const float* __restrict__ Wih1, const float* __restrict__ Whh1,
                              const float* __restrict__ bih0, const float* __restrict__ bhh0,
                              const float* __restrict__ bih1, const float* __restrict__ bhh1,
                              unsigned short* __restrict__ wb, float* __restrict__ bsum,
                              int* __restrict__ flags) {
    int gid = blockIdx.x * blockDim.x + threadIdx.x;   // grid = 896*256 = 229376 = WB_TOT
    float v;
    if      (gid < WB_HH0) v = Wih0[gid];
    else if (gid < WB_IH1) v = Whh0[gid - WB_HH0];
    else if (gid < WB_HH1) v = Wih1[gid - WB_IH1];
    else                   v = Whh1[gid - WB_HH1];
    wb[gid] = f2bf(v);
    if (gid < 512)       bsum[gid] = bih0[gid] + bhh0[gid];
    else if (gid < 1024) bsum[gid] = bih1[gid - 512] + bhh1[gid - 512];
    if (gid < 128) flags[gid] = 0;
}

// ---------------- fused block: 8 rec waves + 8 helper waves ----------------
// 128 blocks x 1024 threads. Blocks 0..63 = layer0 (producer), 64..127 = layer1
// (consumer), paired on batch tile bt. Within a block:
//   waves 0..7  (rec):    h-recurrence. Hold ONLY whh (64 VGPRs) -> no register
//                         overflow (R7's hidden cost: live set >128 forced AGPR
//                         shuffling). Per step: read 4 gate-init floats from LDS
//                         gbuf, ds_read h, 16 MFMAs, 1 cell update/lane, ds_write.
//   waves 8..15 (helper): compute gate-inits g = bsum + A @ Wih^T for 2-step
//                         windows into LDS gbuf (double-buffered), 2 windows
//                         ahead of rec. A = x (producer) or h0 ring (consumer).
// Gate transport stays in LDS (R9's cross-XCD fp32 rings cost 1.5 GB HBM traffic
// and 2.5x time). Inter-block h0 handoff: global ring, CH=16, depth 4, flags.
// Two separate loops with IDENTICAL dynamic barrier counts (16 light + 2 full
// per chunk); wave-level role divergence keeps register pressure independent.
template<int KIN, bool IS_PROD>
__device__ __forceinline__ void lstm_block(
    const unsigned short* __restrict__ ain,   // producer: xb (global layout); consumer: h0 tile base
    const unsigned short* __restrict__ w_ih,  // bf16 [512][KIN]
    const unsigned short* __restrict__ w_hh,  // bf16 [512][128]
    const float* __restrict__ bsum,           // [512] (layer-adjusted)
    unsigned short* __restrict__ h0out,       // producer: h0 tile base
    const float* __restrict__ W1, const float* __restrict__ b1,
    const float* __restrict__ W2, const float* __restrict__ b2,
    float* __restrict__ out,
    int* __restrict__ prodprog, int* __restrict__ consprog, int bt)
{
    constexpr int KT = KIN / 32;
    const int tid  = threadIdx.x;
    const int wave = tid >> 6, lane = tid & 63, quad = lane >> 4, l16 = lane & 15;
    const int b0   = bt * RB;

    // gbuf[sb][io][gate tT][tid]: rec thread reads its 4 gates at stride-512
    // b32 (tid consecutive -> conflict-free); helper stores hit 16 banks 2-way
    // (free). 32 KB. hbuf: proven 16-row layout (rows {0,4,8,12} used; aligned,
    // conflict-free).
    __shared__ float gbuf[2][2][4][512];
    __shared__ short hbuf[2][16][132];
    __shared__ float hl[RB][128];
    __shared__ float mid[RB][65];

    if (wave < 8) {
        // ================= RECURRENCE WAVES =================
        const int cell = wave * 16 + l16;
        const int arow = l16 & 12;
        for (int i = tid; i < 2 * 16 * 132; i += 512) ((short*)hbuf)[i] = 0;

        short8 whh_f[4][4];
#pragma unroll
        for (int tT = 0; tT < 4; tT++)
#pragma unroll
            for (int kt = 0; kt < 4; kt++)
                whh_f[tT][kt] = *(const short8*)(w_hh + (size_t)(tT * 128 + cell) * H + kt * 32 + quad * 8);

        if (!IS_PROD && tid == 0) spin_ge(prodprog, 2);   // h0 chunks 0,1 ready
        __syncthreads();   // B1: spin done -> helpers may load A
        __syncthreads();   // B2: helper prologue (win0 in gbuf[0]) done
        float c0 = 0.f;

        auto rstep = [&](int CUR, int SB, unsigned short* hs, int i, bool last)
            __attribute__((always_inline)) {
            const float* gp = &gbuf[SB][CUR][0][tid];
            short8 ha0 = *(const short8*)&hbuf[CUR][arow][0 * 32 + quad * 8];
            short8 ha1 = *(const short8*)&hbuf[CUR][arow][1 * 32 + quad * 8];
            short8 ha2 = *(const short8*)&hbuf[CUR][arow][2 * 32 + quad * 8];
            short8 ha3 = *(const short8*)&hbuf[CUR][arow][3 * 32 + quad * 8];
            float4v a0 = (float4v){gp[0],    0.f, 0.f, 0.f};
            float4v a1 = (float4v){gp[512],  0.f, 0.f, 0.f};
            float4v a2 = (float4v){gp[1024], 0.f, 0.f, 0.f};
            float4v a3 = (float4v){gp[1536], 0.f, 0.f, 0.f};
            a0 = __builtin_amdgcn_mfma_f32_16x16x32_bf16(ha0, whh_f[0][0], a0, 0, 0, 0);
            a1 = __builtin_amdgcn_mfma_f32_16x16x32_bf16(ha0, whh_f[1][0], a1, 0, 0, 0);
            a2 = __builtin_amdgcn_mfma_f32_16x16x32_bf16(ha0, whh_f[2][0], a2, 0, 0, 0);
            a3 = __builtin_amdgcn_mfma_f32_16x16x32_bf16(ha0, whh_f[3][0], a3, 0, 0, 0);
            a0 = __builtin_amdgcn_mfma_f32_16x16x32_bf16(ha1, whh_f[0][1], a0, 0, 0, 0);
            a1 = __builtin_amdgcn_mfma_f32_16x16x32_bf16(ha1, whh_f[1][1], a1, 0, 0, 0);
            a2 = __builtin_amdgcn_mfma_f32_16x16x32_bf16(ha1, whh_f[2][1], a2, 0, 0, 0);
            a3 = __builtin_amdgcn_mfma_f32_16x16x32_bf16(ha1, whh_f[3][1], a3, 0, 0, 0);
            a0 = __builtin_amdgcn_mfma_f32_16x16x32_bf16(ha2, whh_f[0][2], a0, 0, 0, 0);
            a1 = __builtin_amdgcn_mfma_f32_16x16x32_bf16(ha2, whh_f[1][2], a1, 0, 0, 0);
            a2 = __builtin_amdgcn_mfma_f32_16x16x32_bf16(ha2, whh_f[2][2], a2, 0, 0, 0);
            a3 = __builtin_amdgcn_mfma_f32_16x16x32_bf16(ha2, whh_f[3][2], a3, 0, 0, 0);
            a0 = __builtin_amdgcn_mfma_f32_16x16x32_bf16(ha3, whh_f[0][3], a0, 0, 0, 0);
            a1 = __builtin_amdgcn_mfma_f32_16x16x32_bf16(ha3, whh_f[1][3], a1, 0, 0, 0);
            a2 = __builtin_amdgcn_mfma_f32_16x16x32_bf16(ha3, whh_f[2][3], a2, 0, 0, 0);
            a3 = __builtin_amdgcn_mfma_f32_16x16x32_bf16(ha3, whh_f[3][3], a3, 0, 0, 0);
            float si = sigmoid_fast(a0[0]);
            float sf = sigmoid_fast(a1[0]);
            float tg = tanh_fast(a2[0]);
            float so = sigmoid_fast(a3[0]);
            float cn = fmaf(sf, c0, si * tg);
            c0 = cn;
            float h = so * tanh_fast(cn);
            const unsigned short hb = f2bf(h);
            hbuf[CUR ^ 1][quad * 4][cell] = (short)hb;
            if (IS_PROD) {
                hs[(size_t)(i * 4 + quad) * H + cell] = hb;   // fire-and-forget
            } else if (last) {
                hl[quad][cell] = h;
            }
            light_barrier();
        };

        for (int ch = 0; ch < NCH; ch++) {
            unsigned short* hs = IS_PROD ? h0out + (size_t)(ch & 3) * (64 * H) : nullptr;
            const bool lastCh = (ch == NCH - 1);
#pragma unroll 1
            for (int i = 0; i < CH; i += 4) {
                rstep(0, 0, hs, i + 0, false);
                rstep(1, 0, hs, i + 1, false);
                rstep(0, 1, hs, i + 2, false);
                rstep(1, 1, hs, i + 3, lastCh && (i + 3 == CH - 1));
            }
            __syncthreads();   // B3: drains this wave's global stores before flag
            if (tid == 0) {
                bump(IS_PROD ? prodprog : consprog);
                if (ch + 1 < NCH) {
                    if (IS_PROD) { if (ch + 1 >= 4) spin_ge(consprog, ch - 2); }  // slot reuse
                    else { int t = ch + 3 < NCH ? ch + 3 : NCH; spin_ge(prodprog, t); }
                }
            }
            __syncthreads();   // B4
        }
    } else {
        // ================= HELPER WAVES =================
        const int hw = wave - 8;
        short8 wih_f[4][KT];
        float  bias4[4];
#pragma unroll
        for (int j = 0; j < 4; j++) {
            const int n = hw * 64 + j * 16 + l16;
#pragma unroll
            for (int kt = 0; kt < KT; kt++)
                wih_f[j][kt] = *(const short8*)(w_ih + (size_t)n * KIN + kt * 32 + quad * 8);
            bias4[j] = bsum[n];
        }
        short8 af0[KT], af1[KT];
        const int m   = l16 & 7;      // token in 2-step window (rows 8..15 duplicate)
        const int ro  = m & 3;        // batch row
        const int dio = m >> 2;       // step within window

        auto loadA = [&](short8 (&af)[KT], int tw0) __attribute__((always_inline)) {
            const int t_tok = tw0 + dio;
            const unsigned short* ap;
            if (IS_PROD)
                ap = ain + ((size_t)(b0 + ro) * SEQ + t_tok) * KIN + quad * 8;
            else
                ap = ain + (size_t)((t_tok >> 4) & 3) * (64 * H)
                         + (size_t)((t_tok & 15) * 4 + ro) * H + quad * 8;
#pragma unroll
            for (int kt = 0; kt < KT; kt++) af[kt] = *(const short8*)(ap + kt * 32);
        };
        // compute 2 n-tiles (j = jA, jA+1) of this window into gbuf[SBD]
        auto compWin = [&](short8 (&af)[KT], int SBD, int jA) __attribute__((always_inline)) {
#pragma unroll
            for (int jj = 0; jj < 2; jj++) {
                const int j  = jA + jj;
                const int cg = (hw * 4 + j) & 7;      // rec wave owning these cells
                const int tT = (hw * 4 + j) >> 3;     // gate type
                const float bs = bias4[j];
                float4v acc = (float4v){bs, bs, bs, bs};
#pragma unroll
                for (int kt = 0; kt < KT; kt++)
                    acc = __builtin_amdgcn_mfma_f32_16x16x32_bf16(af[kt], wih_f[j][kt], acc, 0, 0, 0);
                if (quad < 2) {                       // valid tokens: quad = io
#pragma unroll
                    for (int reg = 0; reg < 4; reg++)
                        gbuf[SBD][quad][tT][cg * 64 + reg * 16 + l16] = acc[reg];
                }
            }
        };

        __syncthreads();   // B1 (rec's consumer-spin done -> safe to read h0)
        // prologue: window 0 (steps 0,1) -> gbuf[0]; preload A(window 1)
        loadA(af0, 0);
        compWin(af0, 0, 0);
        compWin(af0, 0, 2);
        loadA(af1, 2);
        __syncthreads();   // B2

        for (int ch = 0; ch < NCH; ch++) {
            const int tb = ch * CH;
#pragma unroll 1
            for (int i = 0; i < CH; i += 4) {
                const int t = tb + i;
                // step t (tp=0,k=0): load A(win t/2+2) -> af0; compute win t/2+1 (j01) -> gbuf[1]
                if (t <= 506) loadA(af0, t + 4);
                if (t <= 508) compWin(af1, 1, 0);
                light_barrier();
                // step t+1: compute win t/2+1 (j23)
                if (t <= 508) compWin(af1, 1, 2);
                light_barrier();
                // step t+2 (tp=1,k=0): load A -> af1; compute win t/2+2 (j01) -> gbuf[0]
                if (t <= 504) loadA(af1, t + 6);
                if (t <= 506) compWin(af0, 0, 0);
                light_barrier();
                // step t+3: compute win t/2+2 (j23)
                if (t <= 506) compWin(af0, 0, 2);
                light_barrier();
            }
            __syncthreads();   // B3
            __syncthreads();   // B4
        }
    }

    if (!IS_PROD) {
        // ---- MLP head (hl visible via final __syncthreads) ----
        if (tid < RB * 64) {
            const int row = tid >> 6, j = tid & 63;
            float s = b1[j];
            const float* wr = W1 + (size_t)j * 128;
#pragma unroll 8
            for (int k = 0; k < 128; k++) s = fmaf(hl[row][k], wr[k], s);
            mid[row][j] = fmaxf(s, 0.f);
        }
        __syncthreads();
        if (tid < RB * 3) {
            const int row = tid / 3, k = tid - row * 3;
            float o = b2[k];
            const float* wr = W2 + (size_t)k * 64;
#pragma unroll 8
            for (int j = 0; j < 64; j++) o = fmaf(mid[row][j], wr[j], o);
            out[(size_t)(b0 + row) * 3 + k] = o;
        }
    }
}

__global__ __launch_bounds__(1024, 4)
void lstm_fused_kernel(const unsigned short* __restrict__ xb,
                       const unsigned short* __restrict__ wb,
                       const float* __restrict__ bsum,
                       unsigned short* __restrict__ h0ring,
                       const float* __restrict__ W1, const float* __restrict__ b1,
                       const float* __restrict__ W2, const float* __restrict__ b2,
                       float* __restrict__ out, int* __restrict__ flags)
{
    int* prodprog = flags;
    int* consprog = flags + 64;
    if (blockIdx.x < 64) {
        const int bt = blockIdx.x;
        lstm_block<64, true>(xb, wb + WB_IH0, wb + WB_HH0, bsum,
                             h0ring + (size_t)bt * (4 * 64 * H),
                             W1, b1, W2, b2, out,
                             &prodprog[bt], &consprog[bt], bt);
    } else {
        const int bt = blockIdx.x - 64;
        lstm_block<128, false>(h0ring + (size_t)bt * (4 * 64 * H),
                               wb + WB_IH1, wb + WB_HH1, bsum + 512,
                               nullptr,
                               W1, b1, W2, b2, out,
                               &prodprog[bt], &consprog[bt], bt);
    }
}

extern "C" void kernel_launch(void* const* d_in, const int* in_sizes, int n_in,
                              void* d_out, int out_size, void* d_ws, size_t ws_size,
                              hipStream_t stream) {
    const float* x     = (const float*)d_in[0];
    const float* W_ih0 = (const float*)d_in[1];
    const float* W_hh0 = (const float*)d_in[2];
    const float* b_ih0 = (const float*)d_in[3];
    const float* b_hh0 = (const float*)d_in[4];
    const float* W_ih1 = (const float*)d_in[5];
    const float* W_hh1 = (const float*)d_in[6];
    const float* b_ih1 = (const float*)d_in[7];
    const float* b_hh1 = (const float*)d_in[8];
    const float* W1    = (const float*)d_in[9];
    const float* b1    = (const float*)d_in[10];
    const float* W2    = (const float*)d_in[11];
    const float* b2    = (const float*)d_in[12];
    float* out = (float*)d_out;

    char* ws = (char*)d_ws;
    unsigned short* xb    = (unsigned short*)(ws + WS_XB);
    unsigned short* h0r   = (unsigned short*)(ws + WS_H0RING);
    unsigned short* wb    = (unsigned short*)(ws + WS_WB);
    float*          bsum  = (float*)(ws + WS_BSUM);
    int*            flags = (int*)(ws + WS_FLAGS);

    conv_x_kernel<<<8192, 256, 0, stream>>>(x, xb);
    prep_w_kernel<<<896, 256, 0, stream>>>(W_ih0, W_hh0, W_ih1, W_hh1,
                                           b_ih0, b_hh0, b_ih1, b_hh1, wb, bsum, flags);
    lstm_fused_kernel<<<128, 1024, 0, stream>>>(xb, wb, bsum, h0r,
                                                W1, b1, W2, b2, out, flags);
}